// Round 6
// baseline (386.645 us; speedup 1.0000x reference)
//
#include <hip/hip_runtime.h>
#include <math.h>

#define NPG    256
#define EPG    4096
#define NGRAPH 1024
#define NATTR  100000

// ---------------- global scratch ----------------
__device__ float  g_F[(size_t)NGRAPH * NPG * 100];     // per-node 97-dim rows (stride 100), ~105 MB
__device__ uint2  g_E[(size_t)NGRAPH * 4104];          // dst-sorted edges {w_bits, src} + 8 sentinels
__device__ int    g_rows[(size_t)NGRAPH * 257];
__device__ float  g_ns[(size_t)NGRAPH * NPG];
__device__ float  g_nd[(size_t)NGRAPH * NPG];
__device__ ushort g_ord[(size_t)NGRAPH * NPG];
__device__ float  g_keys[(size_t)NGRAPH * NPG];

// ================= kernel 1: edge prep =================
extern "C" __global__ void __launch_bounds__(512, 8)
edge_prep(const int* __restrict__ src, const int* __restrict__ dst,
          const int* __restrict__ edge_id, const float* __restrict__ edata)
{
    __shared__ float ewRaw[4096];
    __shared__ uint  rawSD[4096];
    __shared__ int   degI[256], degO[256], cur[256], rowSs[257];

    const int g = blockIdx.x, t = threadIdx.x;
    const int lane = t & 63;
    uint2* gEg = g_E + (size_t)g * 4104;

    if (t < NPG) { degI[t] = 0; degO[t] = 0; }
    __syncthreads();
    for (int e = t; e < EPG; e += 512) {
        const int ge = g * EPG + e;
        const int s = src[ge] - g * NPG;
        const int d = dst[ge] - g * NPG;
        rawSD[e] = (uint)s | ((uint)d << 16);
        ewRaw[e] = edata[edge_id[ge]];
        atomicAdd(&degO[s], 1);
        atomicAdd(&degI[d], 1);
    }
    __syncthreads();
    if (t < 64) {       // single-wave shuffle prefix scan of degI -> rowSs
        const int d0 = degI[4 * t], d1 = degI[4 * t + 1],
                  d2 = degI[4 * t + 2], d3 = degI[4 * t + 3];
        const int p1 = d0, p2 = p1 + d1, p3 = p2 + d2, p4 = p3 + d3;
        int s = p4;
        #pragma unroll
        for (int off = 1; off <= 32; off <<= 1) {
            const int o = __shfl_up(s, off, 64);
            if (lane >= off) s += o;
        }
        const int excl = s - p4;
        rowSs[4 * t + 1] = excl + p1;
        rowSs[4 * t + 2] = excl + p2;
        rowSs[4 * t + 3] = excl + p3;
        rowSs[4 * t + 4] = excl + p4;
        if (t == 0) rowSs[0] = 0;
    }
    __syncthreads();
    if (t < NPG) {
        g_ns[g * NPG + t] = (float)(1.0 / sqrt((double)(degO[t] > 0 ? degO[t] : 1)));
        g_nd[g * NPG + t] = (float)(1.0 / sqrt((double)(degI[t] > 0 ? degI[t] : 1)));
        cur[t] = rowSs[t];
    }
    if (t < 257) g_rows[g * 257 + t] = rowSs[t];
    if (t < 8)   gEg[4096 + t] = make_uint2(0u, 0u);
    __syncthreads();
    for (int e = t; e < EPG; e += 512) {
        const uint sd = rawSD[e];
        const int d = (int)(sd >> 16), s = (int)(sd & 0xffffu);
        const int pos = atomicAdd(&cur[d], 1);
        gEg[pos] = make_uint2(__float_as_uint(ewRaw[e]), (uint)s);
    }
    __syncthreads();
    // degree-sort nodes (counting sort by clamped in-degree) -> g_ord
    if (t < NPG) degO[t] = 0;
    __syncthreads();
    if (t < NPG) atomicAdd(&degO[min(degI[t], 255)], 1);
    __syncthreads();
    if (t < 64) {
        const int d0 = degO[4 * t], d1 = degO[4 * t + 1],
                  d2 = degO[4 * t + 2], d3 = degO[4 * t + 3];
        const int p1 = d0, p2 = p1 + d1, p3 = p2 + d2, p4 = p3 + d3;
        int s = p4;
        #pragma unroll
        for (int off = 1; off <= 32; off <<= 1) {
            const int o = __shfl_up(s, off, 64);
            if (lane >= off) s += o;
        }
        const int excl = s - p4;
        cur[4 * t]     = excl;
        cur[4 * t + 1] = excl + p1;
        cur[4 * t + 2] = excl + p2;
        cur[4 * t + 3] = excl + p3;
    }
    __syncthreads();
    if (t < NPG) {
        const int pos = atomicAdd(&cur[min(degI[t], 255)], 1);
        g_ord[g * NPG + pos] = (ushort)t;
    }
}

// ================= kernel 2: GNN layers =================
// LDS layout (bytes), total 75,904 -> 2 blocks/CU @ 1024 threads
#define A_Y      0        // float[256*36] 36864
#define A_E      36864    // uint2[4104] 32832
#define A_ROWS   69696    // int[257] 1056
#define A_NS     70752    // float[256]
#define A_ND     71776    // float[256]
#define A_BS     72800    // float[97] -> 512
#define A_KEYS   73312    // float[256]
#define A_Y4     74336    // float[256]
#define A_ORD    75360    // ushort[256] 512
#define A_TOTAL  75904

__device__ __forceinline__ void aggregate32(const uint2* sE, const int* rowS,
                                            const ushort* ord, const float* Y,
                                            const float* nd, const float* Bs, int boff,
                                            float* keys, float* __restrict__ gFg, int t)
{
    #pragma unroll
    for (int r = 0; r < 2; ++r) {
        const int n = ord[r * 128 + (t >> 3)];
        const int q = t & 7;
        const int rs = rowS[n], re = rowS[n + 1];
        double a0 = 0.0, a1 = 0.0, a2 = 0.0, a3 = 0.0;
        uint2 e0 = sE[rs];
        uint2 e1 = sE[rs + 1];
        float4 y0 = *(const float4*)(Y + e0.y * 36 + q * 4);
        for (int e = rs; e < re; ++e) {
            const float4 y1 = *(const float4*)(Y + e1.y * 36 + q * 4);
            const uint2 e2 = sE[e + 2];                  // pad-safe
            const double w = (double)__uint_as_float(e0.x);
            a0 += (double)y0.x * w;
            a1 += (double)y0.y * w;
            a2 += (double)y0.z * w;
            a3 += (double)y0.w * w;
            e0 = e1; e1 = e2; y0 = y1;
        }
        const double sc = (double)nd[n];
        float4 hv;
        hv.x = tanhf((float)(a0 * sc) + Bs[boff + q * 4 + 0]);
        hv.y = tanhf((float)(a1 * sc) + Bs[boff + q * 4 + 1]);
        hv.z = tanhf((float)(a2 * sc) + Bs[boff + q * 4 + 2]);
        hv.w = tanhf((float)(a3 * sc) + Bs[boff + q * 4 + 3]);
        *(float4*)(gFg + (size_t)n * 100 + boff + q * 4) = hv;
        float m = fmaxf(fmaxf(hv.x, hv.y), fmaxf(hv.z, hv.w));
        m = fmaxf(m, __shfl_xor(m, 1, 64));
        m = fmaxf(m, __shfl_xor(m, 2, 64));
        m = fmaxf(m, __shfl_xor(m, 4, 64));
        if (q == 0) keys[n] = fmaxf(keys[n], m);
    }
}

extern "C" __global__ void __launch_bounds__(1024, 8)
gnn_layers(const int* __restrict__ feats, const int* __restrict__ node_id,
           const float* __restrict__ ndata, const float* __restrict__ node_emb,
           const float* __restrict__ W0, const float* __restrict__ b0,
           const float* __restrict__ W1, const float* __restrict__ b1,
           const float* __restrict__ W2, const float* __restrict__ b2,
           const float* __restrict__ W3, const float* __restrict__ b3)
{
    extern __shared__ char smem[];
    float*  Y    = (float*)(smem + A_Y);
    uint2*  sE   = (uint2*)(smem + A_E);
    int*    rowS = (int*)(smem + A_ROWS);
    float*  ns   = (float*)(smem + A_NS);
    float*  nd   = (float*)(smem + A_ND);
    float*  Bs   = (float*)(smem + A_BS);
    float*  keys = (float*)(smem + A_KEYS);
    float*  y4   = (float*)(smem + A_Y4);
    ushort* ord  = (ushort*)(smem + A_ORD);

    const int g = blockIdx.x, t = threadIdx.x;
    float* gFg = g_F + (size_t)g * NPG * 100;
    const uint2* gEg = g_E + (size_t)g * 4104;

    for (int i = t; i < 4104; i += 1024) sE[i] = gEg[i];
    if (t < 257) rowS[t] = g_rows[g * 257 + t];
    if (t < NPG) {
        ns[t] = g_ns[g * NPG + t];
        nd[t] = g_nd[g * NPG + t];
        ord[t] = g_ord[g * NPG + t];
        keys[t] = -INFINITY;
    }
    if (t < 97) Bs[t] = (t < 32) ? b0[t] : (t < 64) ? b1[t - 32]
                       : (t < 96) ? b2[t - 64] : b3[0];
    __syncthreads();

    const int j = t & 31, nb = t >> 5;

    // Layer 1: y = (x*ns) @ W0 via 4 input chunks (staged in Y, in-place)
    {
        float acc[8] = {0.f, 0.f, 0.f, 0.f, 0.f, 0.f, 0.f, 0.f};
        for (int c = 0; c < 4; ++c) {
            for (int i = t; i < 2048; i += 1024) {
                const int n = i >> 3, q = i & 7;
                const int gn = g * NPG + n;
                const int nidn = node_id[gn];
                const int j0 = c * 32 + q * 4;
                float4 v;
                if (j0 < 64)      v = *(const float4*)(ndata    + (size_t)nidn * 64 + j0);
                else if (j0 < 96) v = *(const float4*)(node_emb + (size_t)feats[gn] * 32 + (j0 - 64));
                else              v = *(const float4*)(node_emb + (size_t)(NATTR + nidn) * 32 + (j0 - 96));
                const float sc = ns[n];
                float4 o; o.x = v.x * sc; o.y = v.y * sc; o.z = v.z * sc; o.w = v.w * sc;
                *(float4*)(Y + n * 36 + q * 4) = o;
            }
            __syncthreads();
            float wc[32];
            #pragma unroll
            for (int d = 0; d < 32; ++d) wc[d] = W0[(c * 32 + d) * 32 + j];
            #pragma unroll
            for (int i2 = 0; i2 < 8; ++i2) {
                const int n = nb * 8 + i2;
                const float4* ar = (const float4*)(Y + n * 36);
                float a = acc[i2];
                #pragma unroll
                for (int d8 = 0; d8 < 8; ++d8) {
                    const float4 av = ar[d8];
                    a = fmaf(av.x, wc[4 * d8 + 0], a);
                    a = fmaf(av.y, wc[4 * d8 + 1], a);
                    a = fmaf(av.z, wc[4 * d8 + 2], a);
                    a = fmaf(av.w, wc[4 * d8 + 3], a);
                }
                acc[i2] = a;
            }
            __syncthreads();
        }
        #pragma unroll
        for (int i2 = 0; i2 < 8; ++i2) Y[(nb * 8 + i2) * 36 + j] = acc[i2];
        __syncthreads();
        aggregate32(sE, rowS, ord, Y, nd, Bs, 0, keys, gFg, t);
        __syncthreads();
    }

    // Layers 2, 3: y = ns * (h @ W), h read from gF
    for (int L = 0; L < 2; ++L) {
        const float* WL = L ? W2 : W1;
        const int pb = L ? 32 : 0;
        float wc[32];
        #pragma unroll
        for (int d = 0; d < 32; ++d) wc[d] = WL[d * 32 + j];
        float acc[8];
        #pragma unroll
        for (int i2 = 0; i2 < 8; ++i2) {
            const int n = nb * 8 + i2;
            const float4* fr = (const float4*)(gFg + (size_t)n * 100 + pb);
            float a = 0.f;
            #pragma unroll
            for (int d8 = 0; d8 < 8; ++d8) {
                const float4 av = fr[d8];
                a = fmaf(av.x, wc[4 * d8 + 0], a);
                a = fmaf(av.y, wc[4 * d8 + 1], a);
                a = fmaf(av.z, wc[4 * d8 + 2], a);
                a = fmaf(av.w, wc[4 * d8 + 3], a);
            }
            acc[i2] = a * ns[n];
        }
        __syncthreads();
        #pragma unroll
        for (int i2 = 0; i2 < 8; ++i2) Y[(nb * 8 + i2) * 36 + j] = acc[i2];
        __syncthreads();
        aggregate32(sE, rowS, ord, Y, nd, Bs, 32 + L * 32, keys, gFg, t);
        __syncthreads();
    }

    // Layer 4: y4 = ns * (h3 @ W3), scalar aggregate
    if (t < NPG) {
        const float4* fr = (const float4*)(gFg + (size_t)t * 100 + 64);
        float a = 0.f;
        #pragma unroll
        for (int d8 = 0; d8 < 8; ++d8) {
            const float4 h = fr[d8];
            a = fmaf(h.x, W3[4 * d8 + 0], a);
            a = fmaf(h.y, W3[4 * d8 + 1], a);
            a = fmaf(h.z, W3[4 * d8 + 2], a);
            a = fmaf(h.w, W3[4 * d8 + 3], a);
        }
        y4[t] = a * ns[t];
    }
    __syncthreads();
    {
        const int n = ord[t >> 2], p = t & 3;
        const int rs = rowS[n], re = rowS[n + 1];
        double a = 0.0;
        for (int e = rs + p; e < re; e += 4) {
            const uint2 ed = sE[e];
            a += (double)__uint_as_float(ed.x) * (double)y4[ed.y];
        }
        a += __shfl_xor(a, 1, 64);
        a += __shfl_xor(a, 2, 64);
        if (p == 0) {
            const float h = tanhf((float)(a * (double)nd[n]) + Bs[96]);
            gFg[(size_t)n * 100 + 96] = h;
            keys[n] = fmaxf(keys[n], h);
        }
    }
    __syncthreads();
    if (t < NPG) g_keys[g * NPG + t] = keys[t];
}

// ================= kernel 3: head =================
extern "C" __global__ void __launch_bounds__(512, 8)
head_kernel(const float* __restrict__ c1w, const float* __restrict__ c1b,
            const float* __restrict__ c2w, const float* __restrict__ c2b,
            const float* __restrict__ f1w, const float* __restrict__ f1b,
            const float* __restrict__ f2w, const float* __restrict__ f2b,
            float* __restrict__ out)
{
    __shared__ float keys[256];
    __shared__ int   selI[32];
    __shared__ float S30[30 * 100];
    __shared__ float c1wS[1552];
    __shared__ float c2wS[2560];
    __shared__ float L1[480];
    __shared__ float Q[240];
    __shared__ float Rr[352];
    __shared__ float Ff[128];

    const int g = blockIdx.x, t = threadIdx.x;
    const int lane = t & 63, wv = t >> 6;
    const float* gFg = g_F + (size_t)g * NPG * 100;

    if (t < NPG) keys[t] = g_keys[g * NPG + t];
    __syncthreads();

    if (t < 64) {
        // wave 0: top-30, jax.lax.top_k tie semantics (desc value, asc index)
        float kv[4]; int ki[4];
        #pragma unroll
        for (int r = 0; r < 4; ++r) { ki[r] = lane * 4 + r; kv[r] = keys[lane * 4 + r]; }
        for (int it = 0; it < 30; ++it) {
            float bv = kv[0]; int bi = ki[0];
            #pragma unroll
            for (int r = 1; r < 4; ++r)
                if (kv[r] > bv || (kv[r] == bv && ki[r] < bi)) { bv = kv[r]; bi = ki[r]; }
            #pragma unroll
            for (int off = 1; off <= 32; off <<= 1) {
                const float ov = __shfl_xor(bv, off, 64);
                const int   oi = __shfl_xor(bi, off, 64);
                if (ov > bv || (ov == bv && oi < bi)) { bv = ov; bi = oi; }
            }
            if (lane == 0) selI[it] = bi;
            if ((bi >> 2) == lane) kv[bi & 3] = -INFINITY;
        }
    } else {
        for (int i = t - 64; i < 1552; i += 448) c1wS[i] = c1w[i];
        for (int i = t - 64; i < 2560; i += 448) c2wS[i] = c2w[i];
    }
    __syncthreads();

    // bitonic-128 sort (ascending) of the 30 selected rows (from global F)
    for (int k = wv; k < 30; k += 8) {
        const float* fr = gFg + (size_t)selI[k] * 100;
        float v0 = fr[lane];
        float v1 = (lane < 33) ? fr[64 + lane] : INFINITY;
        for (int kk = 2; kk <= 128; kk <<= 1) {
            for (int jj = kk >> 1; jj > 0; jj >>= 1) {
                if (jj == 64) {
                    const float lo = fminf(v0, v1), hi = fmaxf(v0, v1);
                    v0 = lo; v1 = hi;
                } else {
                    const float p0 = __shfl_xor(v0, jj, 64);
                    const float p1 = __shfl_xor(v1, jj, 64);
                    const bool up   = ((lane & jj) == 0);
                    const bool asc0 = (kk == 128) ? true : ((lane & kk) == 0);
                    const bool asc1 = (kk == 128) ? true : (((64 + lane) & kk) == 0);
                    v0 = (up == asc0) ? fminf(v0, p0) : fmaxf(v0, p0);
                    v1 = (up == asc1) ? fminf(v1, p1) : fmaxf(v1, p1);
                }
            }
        }
        S30[k * 100 + lane] = v0;
        if (lane < 33) S30[k * 100 + 64 + lane] = v1;
    }
    __syncthreads();

    // conv1 (16 ch, kernel 97, stride 97) + relu
    if (t < 480) {
        const int k = t >> 4, c = t & 15;
        const float* row  = S30 + k * 100;
        const float* wrow = c1wS + c * 97;
        float acc = c1b[c];
        for (int d = 0; d < 97; ++d) acc = fmaf(row[d], wrow[d], acc);
        L1[k * 16 + c] = fmaxf(acc, 0.f);
    }
    __syncthreads();
    if (t < 240) {
        const int c = t / 15, tt = t % 15;
        Q[c * 15 + tt] = fmaxf(L1[(2 * tt) * 16 + c], L1[(2 * tt + 1) * 16 + c]);
    }
    __syncthreads();
    if (t < 352) {
        const int o = t / 11, tt = t % 11;
        const float* wo = c2wS + o * 80;
        float acc = c2b[o];
        #pragma unroll
        for (int c = 0; c < 16; ++c)
            #pragma unroll
            for (int jj = 0; jj < 5; ++jj)
                acc = fmaf(Q[c * 15 + tt + jj], wo[c * 5 + jj], acc);
        Rr[o * 11 + tt] = fmaxf(acc, 0.f);
    }
    __syncthreads();
    if (t < 128) {
        float acc = f1b[t];
        const float* wr = f1w + t * 352;
        for (int i = 0; i < 352; ++i) acc = fmaf(Rr[i], wr[i], acc);
        Ff[t] = fmaxf(acc, 0.f);
    }
    __syncthreads();
    if (t < 64) {
        float acc = Ff[lane] * f2w[lane] + Ff[lane + 64] * f2w[lane + 64];
        #pragma unroll
        for (int off = 1; off <= 32; off <<= 1) acc += __shfl_xor(acc, off, 64);
        if (lane == 0) out[g] = acc + f2b[0];
    }
}

extern "C" void kernel_launch(void* const* d_in, const int* in_sizes, int n_in,
                              void* d_out, int out_size, void* d_ws, size_t ws_size,
                              hipStream_t stream)
{
    const int*   feats    = (const int*)d_in[0];
    const int*   node_id  = (const int*)d_in[1];
    const int*   edge_id  = (const int*)d_in[2];
    const int*   src      = (const int*)d_in[3];
    const int*   dst      = (const int*)d_in[4];
    const float* ndata    = (const float*)d_in[5];
    const float* edata    = (const float*)d_in[6];
    const float* node_emb = (const float*)d_in[7];
    const float* W0 = (const float*)d_in[8];
    const float* b0 = (const float*)d_in[9];
    const float* W1 = (const float*)d_in[10];
    const float* b1 = (const float*)d_in[11];
    const float* W2 = (const float*)d_in[12];
    const float* b2 = (const float*)d_in[13];
    const float* W3 = (const float*)d_in[14];
    const float* b3 = (const float*)d_in[15];
    const float* c1w = (const float*)d_in[16];
    const float* c1b = (const float*)d_in[17];
    const float* c2w = (const float*)d_in[18];
    const float* c2b = (const float*)d_in[19];
    const float* f1w = (const float*)d_in[20];
    const float* f1b = (const float*)d_in[21];
    const float* f2w = (const float*)d_in[22];
    const float* f2b = (const float*)d_in[23];

    (void)hipFuncSetAttribute((const void*)gnn_layers,
                              hipFuncAttributeMaxDynamicSharedMemorySize, A_TOTAL);

    edge_prep<<<NGRAPH, 512, 0, stream>>>(src, dst, edge_id, edata);
    gnn_layers<<<NGRAPH, 1024, A_TOTAL, stream>>>(feats, node_id, ndata, node_emb,
                                                  W0, b0, W1, b1, W2, b2, W3, b3);
    head_kernel<<<NGRAPH, 512, 0, stream>>>(c1w, c1b, c2w, c2b,
                                            f1w, f1b, f2w, f2b,
                                            (float*)d_out);
}